// Round 11
// baseline (2922.574 us; speedup 1.0000x reference)
//
#include <hip/hip_runtime.h>

#define N_ROWS 8192
#define K_CODES 8192
#define D_DIM 512

typedef unsigned long long u64;

// ---------------------------------------------------------------------------
// Kernel 1: x_sq / e_sq, wave-parallel, bit-exact numpy pairwise emulation
// (validated R9/R10). 32 lanes per row; shfl_xor tree = numpy's add order.
// ---------------------------------------------------------------------------
__global__ __launch_bounds__(256) void vq_sq(const float* __restrict__ x,
                                             const float* __restrict__ emb,
                                             float* __restrict__ x_sq,
                                             float* __restrict__ e_sq) {
  const int t = threadIdx.x;
  const int wave = t >> 6, l = t & 63;
  const int half = l >> 5, ll = l & 31;
  const int q = ll >> 3, j = ll & 7;
  const int row = blockIdx.x * 8 + wave * 2 + half;  // 0..16383
  const float* p =
      (row < N_ROWS) ? (x + (size_t)row * D_DIM)
                     : (emb + (size_t)(row - N_ROWS) * D_DIM);
  const float v0 = p[128 * q + j];
  float r = __fmul_rn(v0, v0);
#pragma unroll
  for (int i = 1; i < 16; ++i) {
    const float v = p[128 * q + 8 * i + j];
    r = __fadd_rn(r, __fmul_rn(v, v));
  }
  r = __fadd_rn(r, __shfl_xor(r, 1, 64));
  r = __fadd_rn(r, __shfl_xor(r, 2, 64));
  r = __fadd_rn(r, __shfl_xor(r, 4, 64));
  r = __fadd_rn(r, __shfl_xor(r, 8, 64));
  r = __fadd_rn(r, __shfl_xor(r, 16, 64));
  if (ll == 0) {
    if (row < N_ROWS) x_sq[row] = r;
    else e_sq[row - N_ROWS] = r;
  }
}

// ---------------------------------------------------------------------------
// Kernel 2: distance + argmin. R8 geometry (64n x 128k, 8 waves, 8n x 2k
// micro-tile) with TWO latency fixes (R10 A/B proved memory-latency-bound):
//
// 1. x staged through the SAME async global_load_lds double-buffer as e
//    (8 KB/chunk). Compute loop touches only LDS; x reads are wave-uniform
//    ds_read_b128 broadcasts (same-address = conflict-free). No global
//    access sits on the FMA critical path anymore.
// 2. L2-locality order: XCD (bx&7) owns nb-supergroup of 16 (2 MB x,
//    L2-resident), sweeps kb-major/nb-minor -> x L2-hot entire sweep,
//    e panel (256 KB) hot per 16 blocks. FETCH 1.06 GB -> ~0.2 GB.
//
// LDS 48 KB/block -> 3 blocks/CU; (512,6) cap ~85 fits ~55-reg working set.
// e-LDS quad-swizzle f(row)=(row>>1)&7 (R8, validated). x-LDS linear.
// FMA chain per output bit-identical to R3-R10 (ascending dd, split@384, _rn).
// ---------------------------------------------------------------------------
__device__ __forceinline__ void compute_chunk(const float* __restrict__ esb,
                                              const float* __restrict__ xsb,
                                              int lane,
                                              float (&acc)[8][2]) {
  const int rbase = lane * 64;  // e row 2*lane
  const int lm = lane & 7;      // f(2*lane+j), j in {0,1}
#pragma unroll
  for (int g = 0; g < 8; ++g) {
    const float* p = esb + rbase + 4 * (g ^ lm);
    const float4 ev0 = *reinterpret_cast<const float4*>(p);       // row 2*lane
    const float4 ev1 = *reinterpret_cast<const float4*>(p + 32);  // row 2*lane+1
#pragma unroll
    for (int r = 0; r < 8; ++r) {
      const float4 xv =
          *reinterpret_cast<const float4*>(xsb + r * 32 + 4 * g);  // uniform
      float a0 = acc[r][0], a1 = acc[r][1];
      a0 = __fmaf_rn(xv.x, ev0.x, a0);
      a0 = __fmaf_rn(xv.y, ev0.y, a0);
      a0 = __fmaf_rn(xv.z, ev0.z, a0);
      a0 = __fmaf_rn(xv.w, ev0.w, a0);
      a1 = __fmaf_rn(xv.x, ev1.x, a1);
      a1 = __fmaf_rn(xv.y, ev1.y, a1);
      a1 = __fmaf_rn(xv.z, ev1.z, a1);
      a1 = __fmaf_rn(xv.w, ev1.w, a1);
      acc[r][0] = a0;
      acc[r][1] = a1;
    }
  }
}

// e-stage: lane t -> 16 B linear dest (float idx 4t + 2048I, I=0..1);
// src row (t>>3)+64I, dd-quad (t&7)^((t>>4)&7)  [inverse of f(row)].
#define STAGE_E(BUF, DD0, I)                                                   \
  __builtin_amdgcn_global_load_lds(                                            \
      (const __attribute__((address_space(1))) void*)(                         \
          e + (size_t)(k0 + (t >> 3) + 64 * (I)) * D_DIM + (DD0) +             \
          4 * ((t & 7) ^ ((t >> 4) & 7))),                                     \
      (__attribute__((address_space(3))) void*)(&es[BUF][4 * t + 2048 * (I)]), \
      16, 0, 0)
// x-stage: lane t -> 16 B linear dest (float idx 4t); src row n0b+(t>>3),
// dd-quad t&7. Layout [64 rows][32 dd], no swizzle (broadcast reads).
#define STAGE_X(BUF, DD0)                                                      \
  __builtin_amdgcn_global_load_lds(                                            \
      (const __attribute__((address_space(1))) void*)(                         \
          x + (size_t)(n0b + (t >> 3)) * D_DIM + (DD0) + 4 * (t & 7)),         \
      (__attribute__((address_space(3))) void*)(&xs[BUF][4 * t]), 16, 0, 0)
#define STAGE(BUF, DD0)                                                        \
  do {                                                                         \
    STAGE_E(BUF, DD0, 0);                                                      \
    STAGE_E(BUF, DD0, 1);                                                      \
    STAGE_X(BUF, DD0);                                                         \
  } while (0)

__global__ __launch_bounds__(512, 6) void vq_dist(
    const float* __restrict__ x, const float* __restrict__ e,
    const float* __restrict__ x_sq, const float* __restrict__ e_sq,
    u64* __restrict__ slots) {
  __shared__ float es[2][4096];  // e: 2 x 16 KB
  __shared__ float xs[2][2048];  // x: 2 x 8 KB

  const int t = threadIdx.x;
  const int lane = t & 63;

  // L2-locality mapping: XCD = bx&7 owns nb in [xcd*16, xcd*16+16)
  // (2 MB of x, L2-resident); within XCD, kb-major / nb-minor.
  const int bx = blockIdx.x;
  const int xcd = bx & 7;
  const int s = bx >> 3;          // 0..1023
  const int kb = s >> 4;          // 0..63
  const int nb = xcd * 16 + (s & 15);
  const int k0 = kb * 128;
  const int n0b = nb * 64;
  const int w = t >> 6;
  const int n0w = __builtin_amdgcn_readfirstlane(n0b + w * 8);
  const float* xsw_base0 = &xs[0][w * 256];  // wave's 8 rows x 32 dd
  const float* xsw_base1 = &xs[1][w * 256];

  float accA[8][2], accB[8][2];
#pragma unroll
  for (int r = 0; r < 8; ++r) {
    accA[r][0] = 0.0f; accA[r][1] = 0.0f;
    accB[r][0] = 0.0f; accB[r][1] = 0.0f;
  }

  // Prologue: fill buffer 0 with chunk 0.
  STAGE(0, 0);
  asm volatile("s_waitcnt vmcnt(0)" ::: "memory");
  __syncthreads();

  // Phase A: chunks 0..11 (dd < 384).
#pragma unroll 1
  for (int c = 0; c < 12; ++c) {
    STAGE((c + 1) & 1, (c + 1) * 32);
    compute_chunk(&es[c & 1][0], (c & 1) ? xsw_base1 : xsw_base0, lane, accA);
    asm volatile("s_waitcnt vmcnt(0)" ::: "memory");
    __syncthreads();
  }
  // Phase B: chunks 12..15 (dd >= 384).
#pragma unroll 1
  for (int c = 12; c < 16; ++c) {
    if (c < 15) STAGE((c + 1) & 1, (c + 1) * 32);
    compute_chunk(&es[c & 1][0], (c & 1) ? xsw_base1 : xsw_base0, lane, accB);
    asm volatile("s_waitcnt vmcnt(0)" ::: "memory");
    __syncthreads();
  }

  // Epilogue: dist = fl(fl(x_sq - 2*dot) + e_sq); packed-key argmin.
  const float4 xsqa = *reinterpret_cast<const float4*>(x_sq + n0w);
  const float4 xsqb = *reinterpret_cast<const float4*>(x_sq + n0w + 4);
  const float xsq[8] = {xsqa.x, xsqa.y, xsqa.z, xsqa.w,
                        xsqb.x, xsqb.y, xsqb.z, xsqb.w};
  const int klane = k0 + 2 * lane;
  const float2 esq = *reinterpret_cast<const float2*>(e_sq + klane);
  const float esqv[2] = {esq.x, esq.y};

#pragma unroll
  for (int r = 0; r < 8; ++r) {
    u64 best = ~0ULL;
#pragma unroll
    for (int j = 0; j < 2; ++j) {
      float dot = __fadd_rn(accA[r][j], accB[r][j]);
      float dist = __fadd_rn(__fsub_rn(xsq[r], __fmul_rn(2.0f, dot)), esqv[j]);
      unsigned int b = __float_as_uint(dist);
      unsigned int sb = (b & 0x80000000u) ? ~b : (b | 0x80000000u);
      u64 key = ((u64)sb << 32) | (unsigned)(klane + j);
      best = best < key ? best : key;
    }
#pragma unroll
    for (int off = 32; off > 0; off >>= 1) {
      u64 o = __shfl_xor((unsigned long long)best, off, 64);
      best = best < o ? best : o;
    }
    if (lane == 0) atomicMin(&slots[n0w + r], best);
  }
}

// ---------------------------------------------------------------------------
// Kernel 3: gather quantized rows (one wave per row), f32 outputs, loss
// partials into 256 hashed f64 buckets.
// ---------------------------------------------------------------------------
__global__ __launch_bounds__(256) void vq_out(
    const float* __restrict__ x, const float* __restrict__ e,
    const u64* __restrict__ slots, float* __restrict__ out_q,
    float* __restrict__ out_idx, double* __restrict__ loss_part) {
  const int t = threadIdx.x;
  const int w = t >> 6, lane = t & 63;
  const int n = blockIdx.x * 4 + w;
  const int idx = (int)(slots[n] & 0xFFFFFFFFULL);
  const float4* qr = (const float4*)(e + (size_t)idx * D_DIM);
  const float4* xr = (const float4*)(x + (size_t)n * D_DIM);
  float4* outr = (float4*)(out_q + (size_t)n * D_DIM);
  double s = 0.0;
#pragma unroll
  for (int i = 0; i < 2; ++i) {
    const int d4 = lane * 2 + i;
    float4 q = qr[d4];
    float4 xv = xr[d4];
    outr[d4] = q;
    double d0 = (double)xv.x - (double)q.x;
    double d1 = (double)xv.y - (double)q.y;
    double d2 = (double)xv.z - (double)q.z;
    double d3 = (double)xv.w - (double)q.w;
    s += d0 * d0 + d1 * d1 + d2 * d2 + d3 * d3;
  }
  for (int off = 32; off > 0; off >>= 1) s += __shfl_down(s, off, 64);
  if (lane == 0) {
    out_idx[n] = (float)idx;
    atomicAdd(&loss_part[(n * 37) & 255], s);
  }
}

__global__ void vq_loss(const double* __restrict__ loss_part,
                        float* __restrict__ out_s) {
  __shared__ double sm[256];
  const int t = threadIdx.x;
  sm[t] = loss_part[t];
  __syncthreads();
  for (int off = 128; off > 0; off >>= 1) {
    if (t < off) sm[t] += sm[t + off];
    __syncthreads();
  }
  if (t == 0) {
    double m = sm[0] / (double)(N_ROWS * D_DIM);
    out_s[0] = (float)(0.25 * m);
    out_s[1] = (float)m;
    out_s[2] = (float)(1.25 * m);
  }
}

extern "C" void kernel_launch(void* const* d_in, const int* in_sizes, int n_in,
                              void* d_out, int out_size, void* d_ws, size_t ws_size,
                              hipStream_t stream) {
  const float* x = (const float*)d_in[0];
  const float* emb = (const float*)d_in[1];
  float* out = (float*)d_out;

  // ws: [0,64K) u64 slots; [64K,96K) f32 x_sq; [96K,128K) f32 e_sq;
  //     [128K,130K) f64 loss_part[256]
  u64* slots = (u64*)d_ws;
  float* x_sq = (float*)((char*)d_ws + 65536);
  float* e_sq = (float*)((char*)d_ws + 98304);
  double* loss_part = (double*)((char*)d_ws + 131072);

  hipMemsetAsync(d_ws, 0xFF, 65536, stream);
  hipMemsetAsync(loss_part, 0, 256 * sizeof(double), stream);

  vq_sq<<<2048, 256, 0, stream>>>(x, emb, x_sq, e_sq);
  vq_dist<<<8192, 512, 0, stream>>>(x, emb, x_sq, e_sq, slots);
  vq_out<<<N_ROWS / 4, 256, 0, stream>>>(x, emb, slots, out,
                                         out + N_ROWS * D_DIM, loss_part);
  vq_loss<<<1, 256, 0, stream>>>(loss_part, out + N_ROWS * D_DIM + N_ROWS);
}

// Round 12
// 936.695 us; speedup vs baseline: 3.1201x; 3.1201x over previous
//
#include <hip/hip_runtime.h>

#define N_ROWS 8192
#define K_CODES 8192
#define D_DIM 512

typedef unsigned long long u64;

// ---------------------------------------------------------------------------
// Kernel 1: x_sq / e_sq, wave-parallel, bit-exact numpy pairwise emulation
// (validated R9-R11). 32 lanes per row; shfl_xor tree = numpy's add order.
// ---------------------------------------------------------------------------
__global__ __launch_bounds__(256) void vq_sq(const float* __restrict__ x,
                                             const float* __restrict__ emb,
                                             float* __restrict__ x_sq,
                                             float* __restrict__ e_sq) {
  const int t = threadIdx.x;
  const int wave = t >> 6, l = t & 63;
  const int half = l >> 5, ll = l & 31;
  const int q = ll >> 3, j = ll & 7;
  const int row = blockIdx.x * 8 + wave * 2 + half;  // 0..16383
  const float* p =
      (row < N_ROWS) ? (x + (size_t)row * D_DIM)
                     : (emb + (size_t)(row - N_ROWS) * D_DIM);
  const float v0 = p[128 * q + j];
  float r = __fmul_rn(v0, v0);
#pragma unroll
  for (int i = 1; i < 16; ++i) {
    const float v = p[128 * q + 8 * i + j];
    r = __fadd_rn(r, __fmul_rn(v, v));
  }
  r = __fadd_rn(r, __shfl_xor(r, 1, 64));
  r = __fadd_rn(r, __shfl_xor(r, 2, 64));
  r = __fadd_rn(r, __shfl_xor(r, 4, 64));
  r = __fadd_rn(r, __shfl_xor(r, 8, 64));
  r = __fadd_rn(r, __shfl_xor(r, 16, 64));
  if (ll == 0) {
    if (row < N_ROWS) x_sq[row] = r;
    else e_sq[row - N_ROWS] = r;
  }
}

// ---------------------------------------------------------------------------
// Kernel 2: distance + argmin.
// R12 change vs R8 (best kernel, 1100us): SMALLER INDEPENDENT BLOCKS.
// 256 threads (4 waves), tile 32n x 128k, same 8n x 2k micro-tile, same
// e-LDS dbuf+swizzle, same 1-deep stage-ahead pipeline, same streaming
// XCD map. LDS 32 KB/block -> 5 resident blocks/CU = 5 INDEPENDENT
// barrier groups: R10 proved 40% of wall was correlated all-wave
// vmcnt(0)+barrier stalls with only 2-3 lockstep 512-thr blocks; five
// staggered groups cover each other's drains.
// R11 lesson applied: x NOT staged (uniform scalar loads); streaming
// k-panel map (marginal-fit L2 plans thrash).
// FMA chain per output bit-identical to R3-R11 (ascending dd, split@384, _rn).
// ---------------------------------------------------------------------------
__device__ __forceinline__ void compute_chunk(const float* __restrict__ esb,
                                              const float* __restrict__ xw,
                                              int dd0, int lane,
                                              float (&acc)[8][2]) {
  const int rbase = lane * 64;  // e row 2*lane
  const int lm = lane & 7;      // swizzle f(2*lane+j), j in {0,1}
#pragma unroll
  for (int g = 0; g < 8; ++g) {
    const float* p = esb + rbase + 4 * (g ^ lm);
    const float4 ev0 = *reinterpret_cast<const float4*>(p);       // row 2*lane
    const float4 ev1 = *reinterpret_cast<const float4*>(p + 32);  // row 2*lane+1
#pragma unroll
    for (int r = 0; r < 8; ++r) {
      const float4 xv =
          *reinterpret_cast<const float4*>(xw + r * D_DIM + dd0 + 4 * g);
      float a0 = acc[r][0], a1 = acc[r][1];
      a0 = __fmaf_rn(xv.x, ev0.x, a0);
      a0 = __fmaf_rn(xv.y, ev0.y, a0);
      a0 = __fmaf_rn(xv.z, ev0.z, a0);
      a0 = __fmaf_rn(xv.w, ev0.w, a0);
      a1 = __fmaf_rn(xv.x, ev1.x, a1);
      a1 = __fmaf_rn(xv.y, ev1.y, a1);
      a1 = __fmaf_rn(xv.z, ev1.z, a1);
      a1 = __fmaf_rn(xv.w, ev1.w, a1);
      acc[r][0] = a0;
      acc[r][1] = a1;
    }
  }
}

// 256 threads stage 16 KB: thread t does I=0..3 16-B loads.
// Linear LDS dest float idx 4t + 1024*I; src row (t>>3)+32*I (row term
// 32I is 0 mod 8 -> swizzle I-independent), src quad (t&7)^((t>>4)&7).
// esrc = per-thread base pointer (hoisted); chunk advance = +32 floats.
#define STAGE(BUF, ESRC)                                                       \
  do {                                                                         \
    __builtin_amdgcn_global_load_lds(                                          \
        (const __attribute__((address_space(1))) void*)(ESRC),                 \
        (__attribute__((address_space(3))) void*)(&es[BUF][4 * t]), 16, 0, 0); \
    __builtin_amdgcn_global_load_lds(                                          \
        (const __attribute__((address_space(1))) void*)((ESRC) + 32 * D_DIM), \
        (__attribute__((address_space(3))) void*)(&es[BUF][4 * t + 1024]),     \
        16, 0, 0);                                                             \
    __builtin_amdgcn_global_load_lds(                                          \
        (const __attribute__((address_space(1))) void*)((ESRC) + 64 * D_DIM), \
        (__attribute__((address_space(3))) void*)(&es[BUF][4 * t + 2048]),     \
        16, 0, 0);                                                             \
    __builtin_amdgcn_global_load_lds(                                          \
        (const __attribute__((address_space(1))) void*)((ESRC) + 96 * D_DIM), \
        (__attribute__((address_space(3))) void*)(&es[BUF][4 * t + 3072]),     \
        16, 0, 0);                                                             \
  } while (0)

__global__ __launch_bounds__(256, 4) void vq_dist(
    const float* __restrict__ x, const float* __restrict__ e,
    const float* __restrict__ x_sq, const float* __restrict__ e_sq,
    u64* __restrict__ slots) {
  __shared__ float es[2][4096];  // 2 x 16 KB

  const int t = threadIdx.x;
  const int lane = t & 63;

  // Streaming XCD map (R8-validated): 16384 blocks; XCD bx&7 owns 8 kb
  // panels, sweeps all 256 nb per panel. e-panel (256 KB) L2-hot; x
  // streams once per panel (FETCH ~1.06 GB total).
  const int bx = blockIdx.x;
  const int swz = (bx & 7) * 2048 + (bx >> 3);
  const int kb = swz >> 8;    // 0..63
  const int nb = swz & 255;   // 0..255
  const int k0 = kb * 128;
  const int n0w = __builtin_amdgcn_readfirstlane(nb * 32 + (t >> 6) * 8);
  const float* xw = x + (size_t)n0w * D_DIM;

  // Hoisted per-thread stage source base (chunk 0); advance 32 floats/chunk.
  const float* esrc =
      e + (size_t)(k0 + (t >> 3)) * D_DIM + 4 * ((t & 7) ^ ((t >> 4) & 7));

  float accA[8][2], accB[8][2];
#pragma unroll
  for (int r = 0; r < 8; ++r) {
    accA[r][0] = 0.0f; accA[r][1] = 0.0f;
    accB[r][0] = 0.0f; accB[r][1] = 0.0f;
  }

  // Prologue: fill buffer 0 with chunk 0.
  STAGE(0, esrc);
  asm volatile("s_waitcnt vmcnt(0)" ::: "memory");
  __syncthreads();

  // Phase A: chunks 0..11 (dd < 384).
#pragma unroll 1
  for (int c = 0; c < 12; ++c) {
    STAGE((c + 1) & 1, esrc + (c + 1) * 32);
    compute_chunk(&es[c & 1][0], xw, c * 32, lane, accA);
    asm volatile("s_waitcnt vmcnt(0)" ::: "memory");
    __syncthreads();
  }
  // Phase B: chunks 12..15 (dd >= 384).
#pragma unroll 1
  for (int c = 12; c < 16; ++c) {
    if (c < 15) STAGE((c + 1) & 1, esrc + (c + 1) * 32);
    compute_chunk(&es[c & 1][0], xw, c * 32, lane, accB);
    asm volatile("s_waitcnt vmcnt(0)" ::: "memory");
    __syncthreads();
  }

  // Epilogue: dist = fl(fl(x_sq - 2*dot) + e_sq); packed-key argmin.
  const float4 xsqa = *reinterpret_cast<const float4*>(x_sq + n0w);
  const float4 xsqb = *reinterpret_cast<const float4*>(x_sq + n0w + 4);
  const float xsq[8] = {xsqa.x, xsqa.y, xsqa.z, xsqa.w,
                        xsqb.x, xsqb.y, xsqb.z, xsqb.w};
  const int klane = k0 + 2 * lane;
  const float2 esq = *reinterpret_cast<const float2*>(e_sq + klane);
  const float esqv[2] = {esq.x, esq.y};

#pragma unroll
  for (int r = 0; r < 8; ++r) {
    u64 best = ~0ULL;
#pragma unroll
    for (int j = 0; j < 2; ++j) {
      float dot = __fadd_rn(accA[r][j], accB[r][j]);
      float dist = __fadd_rn(__fsub_rn(xsq[r], __fmul_rn(2.0f, dot)), esqv[j]);
      unsigned int b = __float_as_uint(dist);
      unsigned int sb = (b & 0x80000000u) ? ~b : (b | 0x80000000u);
      u64 key = ((u64)sb << 32) | (unsigned)(klane + j);
      best = best < key ? best : key;
    }
#pragma unroll
    for (int off = 32; off > 0; off >>= 1) {
      u64 o = __shfl_xor((unsigned long long)best, off, 64);
      best = best < o ? best : o;
    }
    if (lane == 0) atomicMin(&slots[n0w + r], best);
  }
}

// ---------------------------------------------------------------------------
// Kernel 3: gather quantized rows (one wave per row), f32 outputs, loss
// partials into 256 hashed f64 buckets.
// ---------------------------------------------------------------------------
__global__ __launch_bounds__(256) void vq_out(
    const float* __restrict__ x, const float* __restrict__ e,
    const u64* __restrict__ slots, float* __restrict__ out_q,
    float* __restrict__ out_idx, double* __restrict__ loss_part) {
  const int t = threadIdx.x;
  const int w = t >> 6, lane = t & 63;
  const int n = blockIdx.x * 4 + w;
  const int idx = (int)(slots[n] & 0xFFFFFFFFULL);
  const float4* qr = (const float4*)(e + (size_t)idx * D_DIM);
  const float4* xr = (const float4*)(x + (size_t)n * D_DIM);
  float4* outr = (float4*)(out_q + (size_t)n * D_DIM);
  double s = 0.0;
#pragma unroll
  for (int i = 0; i < 2; ++i) {
    const int d4 = lane * 2 + i;
    float4 q = qr[d4];
    float4 xv = xr[d4];
    outr[d4] = q;
    double d0 = (double)xv.x - (double)q.x;
    double d1 = (double)xv.y - (double)q.y;
    double d2 = (double)xv.z - (double)q.z;
    double d3 = (double)xv.w - (double)q.w;
    s += d0 * d0 + d1 * d1 + d2 * d2 + d3 * d3;
  }
  for (int off = 32; off > 0; off >>= 1) s += __shfl_down(s, off, 64);
  if (lane == 0) {
    out_idx[n] = (float)idx;
    atomicAdd(&loss_part[(n * 37) & 255], s);
  }
}

__global__ void vq_loss(const double* __restrict__ loss_part,
                        float* __restrict__ out_s) {
  __shared__ double sm[256];
  const int t = threadIdx.x;
  sm[t] = loss_part[t];
  __syncthreads();
  for (int off = 128; off > 0; off >>= 1) {
    if (t < off) sm[t] += sm[t + off];
    __syncthreads();
  }
  if (t == 0) {
    double m = sm[0] / (double)(N_ROWS * D_DIM);
    out_s[0] = (float)(0.25 * m);
    out_s[1] = (float)m;
    out_s[2] = (float)(1.25 * m);
  }
}

extern "C" void kernel_launch(void* const* d_in, const int* in_sizes, int n_in,
                              void* d_out, int out_size, void* d_ws, size_t ws_size,
                              hipStream_t stream) {
  const float* x = (const float*)d_in[0];
  const float* emb = (const float*)d_in[1];
  float* out = (float*)d_out;

  // ws: [0,64K) u64 slots; [64K,96K) f32 x_sq; [96K,128K) f32 e_sq;
  //     [128K,130K) f64 loss_part[256]
  u64* slots = (u64*)d_ws;
  float* x_sq = (float*)((char*)d_ws + 65536);
  float* e_sq = (float*)((char*)d_ws + 98304);
  double* loss_part = (double*)((char*)d_ws + 131072);

  hipMemsetAsync(d_ws, 0xFF, 65536, stream);
  hipMemsetAsync(loss_part, 0, 256 * sizeof(double), stream);

  vq_sq<<<2048, 256, 0, stream>>>(x, emb, x_sq, e_sq);
  vq_dist<<<16384, 256, 0, stream>>>(x, emb, x_sq, e_sq, slots);
  vq_out<<<N_ROWS / 4, 256, 0, stream>>>(x, emb, slots, out,
                                         out + N_ROWS * D_DIM, loss_part);
  vq_loss<<<1, 256, 0, stream>>>(loss_part, out + N_ROWS * D_DIM + N_ROWS);
}